// Round 14
// baseline (348.672 us; speedup 1.0000x reference)
//
#include <hip/hip_runtime.h>
#include <math.h>

#define N_NODES 50000
#define N_PAD   50048              // rows padded to multiple of 16/64
#define N_EDGES 1600000
#define DIM     128
#define RCUT    5.0f
#define NG16    (N_PAD / 16)       // 3128 groups of 16 nodes
#define NB_PRE  512
#define CH_PRE  (N_EDGES / NB_PRE) // 3125 edges per preA histogram chunk
#define NB_CONV 6250               // convert blocks in preA
#define NB_WPREP 8                 // wprep blocks in preA
#define NB_RE   128                // reorder blocks (4 preA chunks each)
#define CH_RE   (N_EDGES / NB_RE)  // 12500 edges per reorder block
#define XPAD    136                // LDS X tile row stride in bf16 (272 B)
#define NB_MID  104                // kmid grid = 13 x 8 (co-resident)
#define GCHK    13                 // per-thread groups in kmid scan (256*13>=3128)

typedef __attribute__((ext_vector_type(8))) __bf16 bf16x8;
typedef __attribute__((ext_vector_type(4))) float  f32x4;

// ---------------- bf16 helpers ----------------
__device__ __forceinline__ float bf_lo(unsigned int u) { return __uint_as_float(u << 16); }
__device__ __forceinline__ float bf_hi(unsigned int u) { return __uint_as_float(u & 0xffff0000u); }
__device__ __forceinline__ unsigned short f2bf(float x) {
    unsigned int u = __float_as_uint(x);
    u += 0x7fffu + ((u >> 16) & 1u);   // round-to-nearest-even
    return (unsigned short)(u >> 16);
}

// ---------------- preA: convert v->bf16 | W->frags | group-16 histogram ----
__global__ __launch_bounds__(256) void preA_kernel(
        const float* __restrict__ v, unsigned short* __restrict__ vb,
        const float* __restrict__ Aw, uint4* __restrict__ wfrag,
        const int* __restrict__ dst, int* __restrict__ partial,
        int* __restrict__ bar) {
    int b = blockIdx.x;
    if (b < NB_CONV) {
        int i = b * 256 + threadIdx.x;           // exactly N_NODES*DIM/4
        float4 x = ((const float4*)v)[i];
        uint2 o;
        o.x = (unsigned)f2bf(x.x) | ((unsigned)f2bf(x.y) << 16);
        o.y = (unsigned)f2bf(x.z) | ((unsigned)f2bf(x.w) << 16);
        ((uint2*)vb)[i] = o;
    } else if (b < NB_CONV + NB_WPREP) {
        int t = (b - NB_CONV) * 256 + threadIdx.x;   // 0..2047
        if (b == NB_CONV && threadIdx.x <= NB_MID)   // zero arrival lines + rel
            bar[threadIdx.x * 32] = 0;
        int lane = t & 63, nt = (t >> 6) & 7, kk = t >> 9;
        int n  = nt * 16 + (lane & 15);
        int k0 = kk * 32 + (lane >> 4) * 8;
        unsigned short h[8];
        #pragma unroll
        for (int i = 0; i < 8; ++i) h[i] = f2bf(Aw[n * DIM + k0 + i]);
        uint4 o;
        o.x = h[0] | ((unsigned)h[1] << 16); o.y = h[2] | ((unsigned)h[3] << 16);
        o.z = h[4] | ((unsigned)h[5] << 16); o.w = h[6] | ((unsigned)h[7] << 16);
        wfrag[t] = o;
    } else {
        __shared__ int h[NG16];                  // 12.5 KB
        int cb = b - NB_CONV - NB_WPREP, tid = threadIdx.x;
        for (int g = tid; g < NG16; g += 256) h[g] = 0;
        __syncthreads();
        int beg = cb * CH_PRE, end = beg + CH_PRE;
        for (int i = beg + tid; i < end; i += 256)
            atomicAdd(&h[dst[i] >> 4], 1);       // LDS atomic, group-16
        __syncthreads();
        for (int g = tid; g < NG16; g += 256) partial[cb * NG16 + g] = h[g];
    }
}

// ---------------- low-contention grid sync for NB_MID co-resident blocks ---
__device__ __forceinline__ void gsyncm(int* bar) {
    int* rel = bar + NB_MID * 32;
    __syncthreads();
    if (threadIdx.x == 0) {
        __threadfence();                          // release phase-1 stores
        __hip_atomic_store(&bar[blockIdx.x * 32], 1,
                           __ATOMIC_RELAXED, __HIP_MEMORY_SCOPE_AGENT);
    }
    if (blockIdx.x == 0) {
        if (threadIdx.x < NB_MID) {
            int* cp = &bar[threadIdx.x * 32];
            while (__hip_atomic_load(cp, __ATOMIC_RELAXED,
                                     __HIP_MEMORY_SCOPE_AGENT) == 0)
                __builtin_amdgcn_s_sleep(1);
        }
        __syncthreads();                          // all blocks observed
        if (threadIdx.x == 0) {
            __threadfence();
            __hip_atomic_store(rel, 1, __ATOMIC_RELAXED, __HIP_MEMORY_SCOPE_AGENT);
        }
    }
    if (threadIdx.x == 0) {
        while (__hip_atomic_load(rel, __ATOMIC_RELAXED,
                                 __HIP_MEMORY_SCOPE_AGENT) == 0)
            __builtin_amdgcn_s_sleep(1);
        __threadfence();                          // acquire
    }
    __syncthreads();
}

// ---------------- kmid: partial2 + replicated scan + pbase, one barrier ----
// 104 blocks (gb=bid%13 covers g, bb=bid/13 covers b-subchunks of 64).
__global__ __launch_bounds__(256) void kmid_kernel(
        const int* __restrict__ partial,
        int* __restrict__ partial2,
        int* __restrict__ goff,
        int* __restrict__ pbase,
        int* __restrict__ bar) {
    __shared__ int part[256];
    __shared__ int goffL[NG16];                   // 12.5 KB
    int tid = threadIdx.x, bid = blockIdx.x;
    int gb = bid % 13, bb = bid / 13;             // gb 0..12, bb 0..7
    int g = gb * 256 + tid;

    // ---- phase 1: partial2[bb][g] over 64 preA chunks ----
    if (g < NG16) {
        int s = 0;
        int b0 = bb * 64;
        for (int b = b0; b < b0 + 64; ++b) s += partial[b * NG16 + g];
        partial2[bb * NG16 + g] = s;
    }
    gsyncm(bar);

    // ---- phase 2: replicated scan over NG16 group totals ----
    int i0 = tid * GCHK;
    int vv[GCHK]; int s = 0;
    #pragma unroll
    for (int k = 0; k < GCHK; ++k) {
        int i = i0 + k; int t = 0;
        if (i < NG16) {
            #pragma unroll
            for (int b2 = 0; b2 < 8; ++b2) t += partial2[b2 * NG16 + i];
        }
        vv[k] = t; s += t;
    }
    part[tid] = s; __syncthreads();
    for (int d = 1; d < 256; d <<= 1) {
        int val = (tid >= d) ? part[tid - d] : 0;
        __syncthreads(); part[tid] += val; __syncthreads();
    }
    int run = (tid == 0) ? 0 : part[tid - 1];
    #pragma unroll
    for (int k = 0; k < GCHK; ++k) {
        int i = i0 + k;
        if (i < NG16) {
            goffL[i] = run;
            if (bid == 0) goff[i] = run;
            run += vv[k];
        }
    }
    if (bid == 0 && tid == 0) goff[NG16] = N_EDGES;
    __syncthreads();

    // ---- phase 3: pbase for reorder chunks rc = bb*16 .. +15 ----
    if (g < NG16) {
        int r = goffL[g];
        for (int b2 = 0; b2 < bb; ++b2) r += partial2[b2 * NG16 + g];
        #pragma unroll 1
        for (int j = 0; j < 16; ++j) {
            int rc = bb * 16 + j;
            pbase[rc * NG16 + g] = r;
            #pragma unroll
            for (int c = 0; c < 4; ++c) r += partial[(rc * 4 + c) * NG16 + g];
        }
    }
}

// ---------------- reorder into group-16 CSR with 4-bit node tags -----------
__global__ __launch_bounds__(512) void reorder_kernel(
        const float* __restrict__ e,
        const int*   __restrict__ src,
        const int*   __restrict__ dst,
        const float* __restrict__ rs,
        const float* __restrict__ sigma,
        const int*   __restrict__ pbase,
        int2* __restrict__ metaT) {
    __shared__ int base[NG16];                    // 12.5 KB
    __shared__ int cnt[NG16];                     // 12.5 KB
    int b = blockIdx.x, tid = threadIdx.x;
    for (int g = tid; g < NG16; g += 512) { base[g] = pbase[b * NG16 + g]; cnt[g] = 0; }
    __syncthreads();
    float rsv = rs[0], sg = sigma[0];
    int beg = b * CH_RE, end = beg + CH_RE;
    for (int i = beg + tid; i < end; i += 512) {
        float r  = e[i];
        float d  = r - rsv;
        float gauss = expf(-(d * d) / (sg * sg));
        float cut   = 0.5f * cosf(r * (float)(M_PI / (double)RCUT));
        cut = (r < RCUT) ? cut : 0.0f;
        float fe = gauss * cut;
        int dn = dst[i];
        int g  = dn >> 4;
        int lr = atomicAdd(&cnt[g], 1);          // LDS atomic
        metaT[base[g] + lr] = make_int2(src[i] * (DIM * 2) | ((dn & 15) << 24),
                                        __float_as_int(fe));
    }
}

// ---------------- shared gather inner loop (int2 meta, proven) -------------
#define EDGE2(mx, mf, rr)                                        \
    do {                                                         \
        float ff = __int_as_float(mf);                           \
        a0 = fmaf(ff, bf_lo(rr), a0);                            \
        a1 = fmaf(ff, bf_hi(rr), a1);                            \
    } while (0)

__device__ __forceinline__ void gather_node(
        const int2* __restrict__ meta, const char* basec,
        int beg, int end, float& a0, float& a1) {
    int c = beg;
    if ((c & 1) && c < end) {
        int2 m = meta[c];
        unsigned rr = *(const unsigned*)(basec + (unsigned)m.x);
        EDGE2(m.x, m.y, rr);
        ++c;
    }
    for (; c + 16 <= end; c += 16) {
        int4 m0 = *(const int4*)(meta + c);
        int4 m1 = *(const int4*)(meta + c + 2);
        int4 m2 = *(const int4*)(meta + c + 4);
        int4 m3 = *(const int4*)(meta + c + 6);
        int4 m4 = *(const int4*)(meta + c + 8);
        int4 m5 = *(const int4*)(meta + c + 10);
        int4 m6 = *(const int4*)(meta + c + 12);
        int4 m7 = *(const int4*)(meta + c + 14);
        unsigned r0  = *(const unsigned*)(basec + (unsigned)m0.x);
        unsigned r1  = *(const unsigned*)(basec + (unsigned)m0.z);
        unsigned r2  = *(const unsigned*)(basec + (unsigned)m1.x);
        unsigned r3  = *(const unsigned*)(basec + (unsigned)m1.z);
        unsigned r4  = *(const unsigned*)(basec + (unsigned)m2.x);
        unsigned r5  = *(const unsigned*)(basec + (unsigned)m2.z);
        unsigned r6  = *(const unsigned*)(basec + (unsigned)m3.x);
        unsigned r7  = *(const unsigned*)(basec + (unsigned)m3.z);
        unsigned r8  = *(const unsigned*)(basec + (unsigned)m4.x);
        unsigned r9  = *(const unsigned*)(basec + (unsigned)m4.z);
        unsigned r10 = *(const unsigned*)(basec + (unsigned)m5.x);
        unsigned r11 = *(const unsigned*)(basec + (unsigned)m5.z);
        unsigned r12 = *(const unsigned*)(basec + (unsigned)m6.x);
        unsigned r13 = *(const unsigned*)(basec + (unsigned)m6.z);
        unsigned r14 = *(const unsigned*)(basec + (unsigned)m7.x);
        unsigned r15 = *(const unsigned*)(basec + (unsigned)m7.z);
        EDGE2(m0.x, m0.y, r0);  EDGE2(m0.z, m0.w, r1);
        EDGE2(m1.x, m1.y, r2);  EDGE2(m1.z, m1.w, r3);
        EDGE2(m2.x, m2.y, r4);  EDGE2(m2.z, m2.w, r5);
        EDGE2(m3.x, m3.y, r6);  EDGE2(m3.z, m3.w, r7);
        EDGE2(m4.x, m4.y, r8);  EDGE2(m4.z, m4.w, r9);
        EDGE2(m5.x, m5.y, r10); EDGE2(m5.z, m5.w, r11);
        EDGE2(m6.x, m6.y, r12); EDGE2(m6.z, m6.w, r13);
        EDGE2(m7.x, m7.y, r14); EDGE2(m7.z, m7.w, r15);
    }
    if (c + 8 <= end) {
        int4 m0 = *(const int4*)(meta + c);
        int4 m1 = *(const int4*)(meta + c + 2);
        int4 m2 = *(const int4*)(meta + c + 4);
        int4 m3 = *(const int4*)(meta + c + 6);
        unsigned r0 = *(const unsigned*)(basec + (unsigned)m0.x);
        unsigned r1 = *(const unsigned*)(basec + (unsigned)m0.z);
        unsigned r2 = *(const unsigned*)(basec + (unsigned)m1.x);
        unsigned r3 = *(const unsigned*)(basec + (unsigned)m1.z);
        unsigned r4 = *(const unsigned*)(basec + (unsigned)m2.x);
        unsigned r5 = *(const unsigned*)(basec + (unsigned)m2.z);
        unsigned r6 = *(const unsigned*)(basec + (unsigned)m3.x);
        unsigned r7 = *(const unsigned*)(basec + (unsigned)m3.z);
        EDGE2(m0.x, m0.y, r0); EDGE2(m0.z, m0.w, r1);
        EDGE2(m1.x, m1.y, r2); EDGE2(m1.z, m1.w, r3);
        EDGE2(m2.x, m2.y, r4); EDGE2(m2.z, m2.w, r5);
        EDGE2(m3.x, m3.y, r6); EDGE2(m3.z, m3.w, r7);
        c += 8;
    }
    for (; c < end; ++c) {
        int2 m = meta[c];
        unsigned rr = *(const unsigned*)(basec + (unsigned)m.x);
        EDGE2(m.x, m.y, rr);
    }
}

// ---------------- layer 0: tile-local 16-bin tagsort + gather + GEMM -------
// 2-wave 16-node blocks (proven fast shape); the sort is per-tile now.
__global__ __launch_bounds__(128, 8) void layer0_kernel(
        const unsigned short* __restrict__ cur,   // bf16 (= vb for L0)
        const unsigned short* __restrict__ vb,
        const int2*  __restrict__ metaT,          // group-16 CSR, tagged
        const int*   __restrict__ goff,           // [NG16+1]
        int2* __restrict__ meta,                  // out: node-exact CSR
        int*  __restrict__ off,                   // out: node offsets
        const uint4* __restrict__ wfrag,
        const float* __restrict__ bias,
        unsigned short* __restrict__ out_bf) {
    __shared__ unsigned short xlds[16 * XPAD];    // 4352 B
    __shared__ int c16[16], b16[17], cu16[16];
    int tid = threadIdx.x;
    int wv  = tid >> 6, lane = tid & 63;
    int t   = blockIdx.x;
    int sbeg = goff[t], send = goff[t + 1];

    // ---- tagsort: 16-bin count + serial scan + scatter ----
    if (tid < 16) c16[tid] = 0;
    __syncthreads();
    for (int i = sbeg + tid; i < send; i += 128)
        atomicAdd(&c16[(metaT[i].x >> 24) & 15], 1);
    __syncthreads();
    if (tid == 0) {
        int run = 0;
        #pragma unroll
        for (int k = 0; k < 16; ++k) { b16[k] = run; cu16[k] = run; run += c16[k]; }
        b16[16] = run;
    }
    __syncthreads();
    if (tid < 17) {
        int node = t * 16 + tid;
        if (node <= N_NODES) off[node] = sbeg + b16[tid];
    }
    for (int i = sbeg + tid; i < send; i += 128) {
        int2 m = metaT[i];
        int tag = (m.x >> 24) & 15;
        int lr = atomicAdd(&cu16[tag], 1);
        meta[sbeg + lr] = make_int2(m.x & 0x00FFFFFF, m.y);
    }
    __syncthreads();   // meta slice (4 KB, L1/L2-hot) ready; b16 stable

    // ---- gather (offsets from LDS b16) ----
    int n0 = t * 16 + wv * 8;
    int myoff = 0;
    if (lane < 9) myoff = sbeg + b16[wv * 8 + lane];
    const char* basec = (const char*)cur + lane * 4;

    #pragma unroll 1
    for (int q = 0; q < 8; ++q) {
        int nl = wv * 8 + q;
        int n  = n0 + q;
        float a0 = 0.f, a1 = 0.f;
        if (n < N_NODES) {
            unsigned vv = *(const unsigned*)((const char*)vb + (size_t)n * (DIM * 2) + lane * 4);
            a0 = bf_lo(vv); a1 = bf_hi(vv);
            int beg = __builtin_amdgcn_readlane(myoff, q);
            int end = __builtin_amdgcn_readlane(myoff, q + 1);
            gather_node(meta, basec, beg, end, a0, a1);
        }
        *(unsigned*)(xlds + nl * XPAD + lane * 2) =
            (unsigned)f2bf(a0) | ((unsigned)f2bf(a1) << 16);
    }
    __syncthreads();

    // ---- GEMM: both waves cover all 16 rows; wave = col-half ----
    int quad = lane >> 4, l16 = lane & 15;
    f32x4 acc[4];
    #pragma unroll
    for (int j = 0; j < 4; ++j) acc[j] = (f32x4){0.f, 0.f, 0.f, 0.f};

    const unsigned short* xp = xlds + l16 * XPAD + quad * 8;
    #pragma unroll
    for (int kk = 0; kk < 4; ++kk) {
        bf16x8 af = *(const bf16x8*)(xp + kk * 32);
        #pragma unroll
        for (int j = 0; j < 4; ++j) {
            uint4 w = wfrag[(kk * 8 + wv * 4 + j) * 64 + lane];
            bf16x8 bfr = __builtin_bit_cast(bf16x8, w);
            acc[j] = __builtin_amdgcn_mfma_f32_16x16x32_bf16(af, bfr, acc[j], 0, 0, 0);
        }
    }

    int orow0 = t * 16 + quad * 4;
    #pragma unroll
    for (int j = 0; j < 4; ++j) {
        int col = (wv * 4 + j) * 16 + l16;
        float b = bias[col];
        #pragma unroll
        for (int r = 0; r < 4; ++r) {
            int orow = orow0 + r;
            if (orow < N_NODES)
                out_bf[(size_t)orow * DIM + col] = f2bf(fmaxf(acc[j][r] + b, 0.f));
        }
    }
}

// ---------------- layers 1/2: 2-wave 16-node fused gather+GEMM (proven) ----
__global__ __launch_bounds__(128, 8) void layer12_kernel(
        const unsigned short* __restrict__ cur,
        const unsigned short* __restrict__ vb,
        const int2*  __restrict__ meta,
        const int*   __restrict__ off,
        const uint4* __restrict__ wfrag,
        const float* __restrict__ bias,
        unsigned short* __restrict__ out_bf,
        float* __restrict__ out_f,
        int last) {
    __shared__ unsigned short xlds[16 * XPAD];    // 4352 B
    int tid = threadIdx.x;
    int wv  = tid >> 6, lane = tid & 63;          // wv in {0,1}
    int tile = blockIdx.x;
    int n0  = tile * 16 + wv * 8;

    int offidx = n0 + ((lane < 9) ? lane : 8);
    if (offidx > N_NODES) offidx = N_NODES;
    int myoff = off[offidx];
    const char* basec = (const char*)cur + lane * 4;

    #pragma unroll 1
    for (int q = 0; q < 8; ++q) {
        int nl = wv * 8 + q;
        int n  = n0 + q;
        float a0 = 0.f, a1 = 0.f;
        if (n < N_NODES) {
            unsigned vv = *(const unsigned*)((const char*)vb + (size_t)n * (DIM * 2) + lane * 4);
            a0 = bf_lo(vv); a1 = bf_hi(vv);
            int beg = __builtin_amdgcn_readlane(myoff, q);
            int end = __builtin_amdgcn_readlane(myoff, q + 1);
            gather_node(meta, basec, beg, end, a0, a1);
        }
        *(unsigned*)(xlds + nl * XPAD + lane * 2) =
            (unsigned)f2bf(a0) | ((unsigned)f2bf(a1) << 16);
    }
    __syncthreads();

    // ---- GEMM: both waves cover all 16 rows; wave = col-half ----
    int quad = lane >> 4, l16 = lane & 15;
    f32x4 acc[4];
    #pragma unroll
    for (int j = 0; j < 4; ++j) acc[j] = (f32x4){0.f, 0.f, 0.f, 0.f};

    const unsigned short* xp = xlds + l16 * XPAD + quad * 8;
    #pragma unroll
    for (int kk = 0; kk < 4; ++kk) {
        bf16x8 af = *(const bf16x8*)(xp + kk * 32);
        #pragma unroll
        for (int j = 0; j < 4; ++j) {
            uint4 w = wfrag[(kk * 8 + wv * 4 + j) * 64 + lane];
            bf16x8 bfr = __builtin_bit_cast(bf16x8, w);
            acc[j] = __builtin_amdgcn_mfma_f32_16x16x32_bf16(af, bfr, acc[j], 0, 0, 0);
        }
    }

    int orow0 = tile * 16 + quad * 4;
    #pragma unroll
    for (int j = 0; j < 4; ++j) {
        int col = (wv * 4 + j) * 16 + l16;
        float b = bias[col];
        #pragma unroll
        for (int r = 0; r < 4; ++r) {
            int orow = orow0 + r;
            if (orow < N_NODES) {
                float val = fmaxf(acc[j][r] + b, 0.f);
                if (last) out_f[(size_t)orow * DIM + col] = val;
                else      out_bf[(size_t)orow * DIM + col] = f2bf(val);
            }
        }
    }
}

// ---------------------------------------------------------------------------
extern "C" void kernel_launch(void* const* d_in, const int* in_sizes, int n_in,
                              void* d_out, int out_size, void* d_ws, size_t ws_size,
                              hipStream_t stream) {
    const float* v     = (const float*)d_in[0];
    const float* e     = (const float*)d_in[1];
    const int*   src   = (const int*)  d_in[2];
    const int*   dst   = (const int*)  d_in[3];
    const float* Aw    = (const float*)d_in[4];
    const float* Ab    = (const float*)d_in[5];
    const float* rs    = (const float*)d_in[6];
    const float* sigma = (const float*)d_in[7];
    float* out = (float*)d_out;

    // ---- workspace layout (~51.6 MB) ----
    char* p = (char*)d_ws;
    int2*           meta  = (int2*)p;            p += (size_t)N_EDGES * 8;       // 12.8 MB (final CSR)
    unsigned short* bufV  = (unsigned short*)p;  p += (size_t)N_PAD * DIM * 2;   // 12.81 MB (pristine bf16 v)
    unsigned short* bufA  = (unsigned short*)p;  p += (size_t)N_PAD * DIM * 2;   // 12.81 MB (metaT / L1 out)
    unsigned short* bufB  = (unsigned short*)p;  p += (size_t)N_PAD * DIM * 2;   // 12.81 MB (partials / L0 out)
    uint4*          wfrag = (uint4*)p;           p += 2048 * 16;                 //  32 KB
    int*            off   = (int*)p;             p += (size_t)(N_NODES + 2) * 4;
    int*            goff  = (int*)p;             p += (NG16 + 2) * 4;            // 12.5 KB
    int*            bar   = (int*)p;             p += (NB_MID + 1) * 32 * 4;     // 13.4 KB
    // aliases (dead before host buffer's first real write):
    int2* metaT    = (int2*)bufA;                // unsorted group-16 CSR, dead after layer0
    int*  partial  = (int*)bufB;                 // [512][NG16] = 6.41 MB
    int*  pbase    = partial + NB_PRE * NG16;    // [128][NG16] = 1.60 MB
    int*  partial2 = pbase + NB_RE * NG16;       // [8][NG16]   = 100 KB  (total 8.11 MB < bufB)

    // preA also zeroes the kmid barrier words (stream-ordered before kmid)
    preA_kernel<<<NB_CONV + NB_WPREP + NB_PRE, 256, 0, stream>>>(
        v, bufV, Aw, wfrag, dst, partial, bar);
    // merged partial-sum + scan + base (104 co-resident blocks, one grid sync)
    kmid_kernel<<<NB_MID, 256, 0, stream>>>(partial, partial2, goff, pbase, bar);
    reorder_kernel<<<NB_RE, 512, 0, stream>>>(e, src, dst, rs, sigma, pbase, metaT);

    // L0: tile-local tagsort + gather(bufV) + gemm -> bufB (consumes metaT)
    layer0_kernel<<<NG16, 128, 0, stream>>>(
        bufV, bufV, metaT, goff, meta, off, wfrag, Ab, bufB);
    // L1: gather(bufB) + gemm -> bufA
    layer12_kernel<<<NG16, 128, 0, stream>>>(
        bufB, bufV, meta, off, wfrag, Ab, bufA, nullptr, 0);
    // L2: gather(bufA) + gemm -> out (fp32)
    layer12_kernel<<<NG16, 128, 0, stream>>>(
        bufA, bufV, meta, off, wfrag, Ab, nullptr, out, 1);
}